// Round 3
// baseline (257.547 us; speedup 1.0000x reference)
//
#include <hip/hip_runtime.h>

// QuantilePreprocessing via direct tabulation of the per-feature composite
// g_f(x) = clip(probit(clip((idx+interp)/1000)), -100, 100), fp16 table.
//
// R3 change vs R2: table entries fp16 (73,920 B vs 147,840 B) -> 2 blocks/CU
// (32 waves/CU instead of 16). R2 was latency-bound: VALU 27%, HBM 30%,
// occupancy 36% -- doubling resident waves doubles bytes in flight.
// fp16 quantization adds <=0.003 abs error on |g|<=5 (budget 2.0, R2 used 0.41).

#define QN 1000
#define NF 32
#define MID_N 641                    // 640 cells over [q1, q998]
#define TL_N 257                     // 256 cells per tail table
#define TBL_HALFS (MID_N*NF + 2*TL_N*NF)    // 36,960
#define TBL_BYTES (TBL_HALFS * 2)           // 73,920 -> 2 blocks/CU
#define LB_OFF (NF * MID_N)                 // left-tail base
#define RB_OFF (NF * (MID_N + TL_N))        // right-tail base (= LB_OFF + 8224)

__device__ __forceinline__ float probit100(float y) {
  if (y <= 0.0f) return -100.0f;
  if (y >= 1.0f) return 100.0f;
  float t = 4.0f * y * (1.0f - y);
  float s = 2.0f * y - 1.0f;
  float w = -__logf(t);
  float p;
  if (w < 5.0f) {
    float u = w - 2.5f;
    p = 2.81022636e-08f;
    p = fmaf(p, u, 3.43273939e-07f);
    p = fmaf(p, u, -3.5233877e-06f);
    p = fmaf(p, u, -4.39150654e-06f);
    p = fmaf(p, u, 0.00021858087f);
    p = fmaf(p, u, -0.00125372503f);
    p = fmaf(p, u, -0.00417768164f);
    p = fmaf(p, u, 0.246640727f);
    p = fmaf(p, u, 1.50140941f);
  } else {
    float u = fminf(sqrtf(w) - 3.0f, 2.1f);
    p = -0.000200214257f;
    p = fmaf(p, u, 0.000100950558f);
    p = fmaf(p, u, 0.00134934322f);
    p = fmaf(p, u, -0.00367342844f);
    p = fmaf(p, u, 0.00573950773f);
    p = fmaf(p, u, -0.0076224613f);
    p = fmaf(p, u, 0.00943887047f);
    p = fmaf(p, u, 1.00167406f);
    p = fmaf(p, u, 2.83297682f);
  }
  float r = 1.41421356237f * p * s;
  return fminf(fmaxf(r, -100.0f), 100.0f);
}

// Exact reference pipeline for one value v, feature f (quantiles L2-resident).
__device__ float eval_node(const float* __restrict__ q, int f, float v) {
  int lo = 0, hi = QN;
  while (lo < hi) {
    int mid = (lo + hi) >> 1;
    if (q[mid * 32 + f] < v) lo = mid + 1; else hi = mid;
  }
  int idx = min(max(lo, 1), QN - 1) - 1;
  float a = q[idx * 32 + f], b = q[(idx + 1) * 32 + f];
  float diff = b - a;
  float safe = (diff == 0.0f) ? 1.0f : diff;
  float interp = (diff == 0.0f) ? 0.5f : (v - a) / safe;
  float y = ((float)idx + interp) / 1000.0f;
  y = fminf(fmaxf(y, 0.0f), 1.0f);
  return probit100(y);
}

__global__ void build_kernel(const float* __restrict__ q, _Float16* __restrict__ tbl) {
  int id = blockIdx.x * 256 + threadIdx.x;
  if (id >= TBL_HALFS) return;
  int f = id & 31, slot = id >> 5;
  float qa = q[f];
  float q1 = q[32 + f];
  float q8 = q[998 * 32 + f];
  float q9 = q[999 * 32 + f];
  float pos; int outIdx;
  if (slot < MID_N) {
    float h = (q8 - q1) * (1.0f / 640.0f);
    pos = q1 + (float)slot * h;
    outIdx = f * MID_N + slot;
  } else if (slot < MID_N + TL_N) {
    int n = slot - MID_N;
    float h = (q1 - qa) * (1.0f / 256.0f);
    float nn = (n == 0) ? 0.0625f : (float)n;   // inset: keep -100 off node 0
    pos = qa + nn * h;
    outIdx = LB_OFF + f * TL_N + n;
  } else {
    int n = slot - MID_N - TL_N;
    float d = q9 - q8;
    float h = d * (2.0f / 256.0f);              // span [q998, q998 + 2*d]
    float nn = (n == TL_N - 1) ? 255.9375f : (float)n;  // inset: keep +100 off last node
    pos = q8 + nn * h;
    outIdx = RB_OFF + f * TL_N + n;
  }
  tbl[outIdx] = (_Float16)eval_node(q, f, pos);
}

__global__ __launch_bounds__(1024, 8) void qp_main(
    const float* __restrict__ x, const float* __restrict__ q,
    const _Float16* __restrict__ tbl, float* __restrict__ out, int nrows) {
  extern __shared__ _Float16 lds[];
  const int t = threadIdx.x;

  // ---- stage table global -> LDS, coalesced 16B ----
  {
    const uint4* tg = (const uint4*)tbl;
    uint4* l4 = (uint4*)lds;
    for (int i = t; i < TBL_BYTES / 16; i += 1024) l4[i] = tg[i];
  }
  __syncthreads();

  // ---- per-feature params (this thread's 4 features) ----
  const int c8 = t & 7, rowo = t >> 3, f0 = c8 << 2;
  float qa[4], q1f[4], q98[4], qz[4], l_inv[4], m_inv[4], r_inv[4];
  int mb[4], lb[4];
#pragma unroll
  for (int j = 0; j < 4; j++) {
    int f = f0 + j;
    qa[j]  = q[f];
    q1f[j] = q[32 + f];
    q98[j] = q[998 * 32 + f];
    qz[j]  = q[999 * 32 + f];
    float d = qz[j] - q98[j];
    m_inv[j] = 640.0f / (q98[j] - q1f[j]);
    l_inv[j] = 256.0f / (q1f[j] - qa[j]);
    r_inv[j] = (d == 0.0f) ? 0.0f : 128.0f / d;  // guard NaN path
    mb[j] = f * MID_N;
    lb[j] = LB_OFF + f * TL_N;
  }

  const int iters = nrows >> 7;     // 128 rows per block-iter
  int it = blockIdx.x;
  float4 xv = make_float4(0.f, 0.f, 0.f, 0.f);
  if (it < iters) {
    int row = (it << 7) + rowo;
    xv = *(const float4*)(x + ((size_t)row << 5) + f0);
  }
  while (it < iters) {
    int itn = it + gridDim.x;
    float4 xn = xv;
    if (itn < iters) {              // uniform prefetch of next tile
      int rown = (itn << 7) + rowo;
      xn = *(const float4*)(x + ((size_t)rown << 5) + f0);
    }

    float xa[4] = {xv.x, xv.y, xv.z, xv.w};
    float res[4];
#pragma unroll
    for (int j = 0; j < 4; j++) {
      float xj = xa[j];
      bool inL = xj < q1f[j];
      bool inR = xj > q98[j];
      float org = inL ? qa[j]    : (inR ? q98[j]        : q1f[j]);
      float inv = inL ? l_inv[j] : (inR ? r_inv[j]      : m_inv[j]);
      int   bas = inL ? lb[j]    : (inR ? lb[j] + NF*TL_N : mb[j]);
      int  ncm1 = (inL || inR) ? (TL_N - 2) : (MID_N - 2);
      float u = (xj - org) * inv;
      int i = (int)u;
      i = min(i, ncm1);
      i = max(i, 0);
      float frac = u - (float)i;
      float T0 = (float)lds[bas + i];
      float T1 = (float)lds[bas + i + 1];
      float val = fmaf(frac, T1 - T0, T0);
      // exact +100 saturation (replicates ref f32 chain; rare, predicated)
      if (xj > qz[j]) {
        float d = qz[j] - q98[j];
        float safe = (d == 0.0f) ? 1.0f : d;
        float interp = (d == 0.0f) ? 0.5f : (xj - q98[j]) / safe;
        if (998.0f + interp >= 1000.0f) val = 100.0f;
      }
      // exact -100 tail: cnt==0 <=> x <= q0 (bit-exact f32 compare)
      val = (xj <= qa[j]) ? -100.0f : val;
      res[j] = val;
    }

    int row = (it << 7) + rowo;
    *(float4*)(out + ((size_t)row << 5) + f0) =
        make_float4(res[0], res[1], res[2], res[3]);

    xv = xn;
    it = itn;
  }
}

// ======================= round-1 fallback (ws too small) ====================
#define G_CELLS 512
#define NT (G_CELLS + 3)
#define LDS_Q_BYTES (QN * NF * 4)
#define LDS_TB_BYTES (NT * NF * 2)
#define LDS_TOTAL (LDS_Q_BYTES + LDS_TB_BYTES)

__device__ __forceinline__ int qoff(int mid, int f) {
  return (mid << 5) + (f ^ (mid & 31));
}
__device__ __forceinline__ int toff(int c, int f) {
  return (c << 5) + (f ^ (c & 31));
}

__global__ __launch_bounds__(1024, 4) void qp_kernel(
    const float* __restrict__ x, const float* __restrict__ q,
    float* __restrict__ out, int nrows) {
  extern __shared__ char smem[];
  float* qs = (float*)smem;
  unsigned short* tb = (unsigned short*)(smem + LDS_Q_BYTES);
  const int t = threadIdx.x;
  for (int i = t; i < QN * NF; i += 1024) {
    int mid = i >> 5, f = i & 31;
    qs[qoff(mid, f)] = q[i];
  }
  __syncthreads();
  for (int k = t; k < NT * NF; k += 1024) {
    int c = k >> 5, f = k & 31;
    unsigned short val;
    if (c == 0) val = 0;
    else if (c == NT - 1) val = (unsigned short)QN;
    else {
      float v = -4.0f + (float)(c - 1) * 0.015625f;
      int lo = 0, hi = QN;
      while (lo < hi) {
        int mid = (lo + hi) >> 1;
        if (qs[qoff(mid, f)] < v) lo = mid + 1; else hi = mid;
      }
      val = (unsigned short)lo;
    }
    tb[toff(c, f)] = val;
  }
  __syncthreads();
  const int c8 = t & 7, rowo = t >> 3, f0 = c8 << 2;
  const int iters = nrows >> 7;
  int it = blockIdx.x;
  float4 xv = make_float4(0.f, 0.f, 0.f, 0.f);
  if (it < iters) {
    int row = (it << 7) + rowo;
    xv = *(const float4*)(x + ((size_t)row << 5) + f0);
  }
  while (it < iters) {
    int itn = it + gridDim.x;
    float4 xn = xv;
    if (itn < iters) {
      int rown = (itn << 7) + rowo;
      xn = *(const float4*)(x + ((size_t)rown << 5) + f0);
    }
    float xa[4] = {xv.x, xv.y, xv.z, xv.w};
    int blo[4], bhi[4];
#pragma unroll
    for (int j = 0; j < 4; j++) {
      int f = f0 + j;
      int cg = (int)floorf((xa[j] + 4.0f) * 64.0f);
      cg = max(min(cg, G_CELLS), -1) + 1;
      int cl = max(cg - 1, 0);
      blo[j] = tb[toff(cl, f)];
      bhi[j] = tb[toff(cg + 1, f)];
    }
#pragma unroll
    for (int s = 0; s < 5; s++) {
#pragma unroll
      for (int j = 0; j < 4; j++) {
        int f = f0 + j;
        int lo = blo[j], hi = bhi[j];
        int mid = (lo + hi) >> 1;
        float qm = qs[qoff(mid, f)];
        bool go = lo < hi;
        bool less = qm < xa[j];
        blo[j] = (go && less) ? mid + 1 : lo;
        bhi[j] = (go && !less) ? mid : hi;
      }
    }
    float res[4];
#pragma unroll
    for (int j = 0; j < 4; j++) {
      int f = f0 + j;
      while (blo[j] < bhi[j]) {
        int mid = (blo[j] + bhi[j]) >> 1;
        if (qs[qoff(mid, f)] < xa[j]) blo[j] = mid + 1; else bhi[j] = mid;
      }
      int cnt = blo[j];
      int idx = min(max(cnt, 1), QN - 1) - 1;
      float lo = qs[qoff(idx, f)];
      float hi = qs[qoff(idx + 1, f)];
      float diff = hi - lo;
      float interp = (diff == 0.0f) ? 0.5f : __fdividef(xa[j] - lo, diff);
      float y = ((float)idx + interp) * 0.001f;
      y = fminf(fmaxf(y, 0.0f), 1.0f);
      res[j] = probit100(y);
    }
    int row = (it << 7) + rowo;
    *(float4*)(out + ((size_t)row << 5) + f0) =
        make_float4(res[0], res[1], res[2], res[3]);
    xv = xn;
    it = itn;
  }
}
// ===========================================================================

extern "C" void kernel_launch(void* const* d_in, const int* in_sizes, int n_in,
                              void* d_out, int out_size, void* d_ws, size_t ws_size,
                              hipStream_t stream) {
  const float* x = (const float*)d_in[0];
  const float* q = (const float*)d_in[1];
  float* out = (float*)d_out;
  int n = in_sizes[0];
  int nrows = n / NF;

  if (ws_size >= (size_t)TBL_BYTES) {
    _Float16* tbl = (_Float16*)d_ws;
    build_kernel<<<(TBL_HALFS + 255) / 256, 256, 0, stream>>>(q, tbl);
    hipFuncSetAttribute((const void*)qp_main,
                        hipFuncAttributeMaxDynamicSharedMemorySize, TBL_BYTES);
    qp_main<<<dim3(512), dim3(1024), TBL_BYTES, stream>>>(x, q, tbl, out, nrows);
  } else {
    hipFuncSetAttribute((const void*)qp_kernel,
                        hipFuncAttributeMaxDynamicSharedMemorySize, LDS_TOTAL);
    qp_kernel<<<dim3(256), dim3(1024), LDS_TOTAL, stream>>>(x, q, out, nrows);
  }
}